// Round 6
// baseline (1866.299 us; speedup 1.0000x reference)
//
#include <hip/hip_runtime.h>
#include <math.h>

#define N_NODES 50000
#define N_EDGES 800000
#define H 96
#define QKV_N 288

#define NPB1 32   // nodes per block, qkv kernel
#define NPB3 32   // nodes per block, node kernel
#define NT3 384   // node kernel threads: 4 parity groups x 96 cols

typedef __attribute__((ext_vector_type(8))) short short8;   // 8 bf16 = 4 VGPRs
typedef __attribute__((ext_vector_type(4))) float f32x4;    // MFMA accumulator

// float -> bf16 (RNE)
__device__ __forceinline__ short f2bf(float f) {
    union { float f; unsigned u; } v; v.f = f;
    unsigned r = v.u + 0x7FFFu + ((v.u >> 16) & 1u);
    return (short)(r >> 16);
}
__device__ __forceinline__ float bf2f(unsigned short h) {
    union { unsigned u; float f; } v; v.u = ((unsigned)h) << 16;
    return v.f;
}

// load 8 contiguous f32 -> hi/lo bf16x8 split fragments (bf16x3 trick)
__device__ __forceinline__ void ld_frag_split(const float* __restrict__ p,
                                              short8& hi, short8& lo) {
    float4 a = *(const float4*)p;
    float4 b = *(const float4*)(p + 4);
    float f[8] = {a.x, a.y, a.z, a.w, b.x, b.y, b.z, b.w};
    #pragma unroll
    for (int j = 0; j < 8; ++j) {
        short h = f2bf(f[j]);
        hi[j] = h;
        lo[j] = f2bf(f[j] - bf2f((unsigned short)h));
    }
}

// ---------------------------------------------------------------------------
// Kernel 1: qkv[n, t] = dot(x[n, :], qkv_w[t, :]) + qkv_b[t]   (t < 288)
// ---------------------------------------------------------------------------
__global__ __launch_bounds__(QKV_N) void qkv_kernel(
    const float* __restrict__ x, const float* __restrict__ qw,
    const float* __restrict__ qb, float* __restrict__ qkv)
{
    __shared__ __align__(16) float xs[H];
    const int t = threadIdx.x;

    float w[H];
    #pragma unroll
    for (int k4 = 0; k4 < H; k4 += 4) {
        float4 v = *(const float4*)(qw + (size_t)t * H + k4);
        w[k4] = v.x; w[k4 + 1] = v.y; w[k4 + 2] = v.z; w[k4 + 3] = v.w;
    }
    const float bias = qb[t];

    const int n0 = blockIdx.x * NPB1;
    for (int nn = 0; nn < NPB1; ++nn) {
        const int node = n0 + nn;
        if (node >= N_NODES) break;          // block-uniform
        __syncthreads();
        if (t < H) xs[t] = x[(size_t)node * H + t];
        __syncthreads();
        float acc = bias;
        #pragma unroll
        for (int k4 = 0; k4 < H; k4 += 4) {
            float4 c = *(const float4*)(xs + k4);
            acc += c.x * w[k4] + c.y * w[k4 + 1] + c.z * w[k4 + 2] + c.w * w[k4 + 3];
        }
        qkv[(size_t)node * QKV_N + t] = acc;
    }
}

// ---------------------------------------------------------------------------
// CSR build: histogram -> scan -> scatter   (proven R4/R5)
// ---------------------------------------------------------------------------
__global__ __launch_bounds__(256) void hist_kernel(const int* __restrict__ eidx,
                                                   int* __restrict__ hist) {
    const int e = blockIdx.x * 256 + threadIdx.x;
    if (e < N_EDGES) atomicAdd(&hist[eidx[e]], 1);
}

#define SCAN_CH 49   // 1024*49 = 50176 >= 50000
__global__ __launch_bounds__(1024) void scan_kernel(int* __restrict__ hist,
                                                    int* __restrict__ rowptr) {
    __shared__ int sums[1024];
    const int t = threadIdx.x;
    const int st = t * SCAN_CH;
    int loc = 0;
    for (int k = 0; k < SCAN_CH; ++k) {
        const int i = st + k;
        if (i < N_NODES) loc += hist[i];
    }
    sums[t] = loc;
    __syncthreads();
    for (int off = 1; off < 1024; off <<= 1) {
        int add = (t >= off) ? sums[t - off] : 0;
        __syncthreads();
        sums[t] += add;
        __syncthreads();
    }
    int run = sums[t] - loc;     // exclusive prefix of this thread's chunk
    for (int k = 0; k < SCAN_CH; ++k) {
        const int i = st + k;
        if (i < N_NODES) {
            const int v = hist[i];
            rowptr[i] = run;
            hist[i]   = run;     // hist becomes the scatter cursor
            run += v;
        }
    }
    if (t == 1023) rowptr[N_NODES] = run;   // = N_EDGES
}

__global__ __launch_bounds__(256) void scatter_kernel(const int* __restrict__ eidx,
                                                      int* __restrict__ cursor,
                                                      int* __restrict__ bucket,
                                                      int* __restrict__ bsrc) {
    const int e = blockIdx.x * 256 + threadIdx.x;
    if (e < N_EDGES) {
        const int dst = eidx[e];
        const int src = eidx[N_EDGES + e];
        const int pos = atomicAdd(&cursor[dst], 1);
        bucket[pos] = e;
        bsrc[pos]   = src;
    }
}

// ---------------------------------------------------------------------------
// Kernel 2 (MFMA, bf16x3 split) — MFMA/staging verbatim from R5.
// Pointwise: quad-lane q4 owns 24 CONTIGUOUS cols -> float4 Q/K/co, b128 LDS.
// ---------------------------------------------------------------------------
#define TILE_E 64
#define EH_LD 196

__global__ __launch_bounds__(256) void edge_kernel(
    const float* __restrict__ conn, const int* __restrict__ eidx,
    const float* __restrict__ qkv,
    const float* __restrict__ ew, const float* __restrict__ eb,
    float* __restrict__ out_e)
{
    __shared__ float eh[TILE_E * EH_LD];      // 64 x 196 f32 = 50176 B

    const int t    = threadIdx.x;
    const int wave = t >> 6;
    const int lane = t & 63;
    const int lr   = lane & 15;
    const int lg16 = lane >> 4;

    // ---- B fragments (hi+lo): e_w rows are B^T rows ----
    short8 bwh[3][3], bwl[3][3];
    #pragma unroll
    for (int f = 0; f < 3; ++f) {
        const int tcol = 16 * (3 * wave + f) + lr;
        #pragma unroll
        for (int kc = 0; kc < 3; ++kc)
            ld_frag_split(ew + (size_t)tcol * H + 32 * kc + 8 * lg16,
                          bwh[f][kc], bwl[f][kc]);
    }

    const int e0 = blockIdx.x * TILE_E;

    f32x4 acc[4][3];
    #pragma unroll
    for (int mt = 0; mt < 4; ++mt)
        #pragma unroll
        for (int f = 0; f < 3; ++f)
            acc[mt][f] = (f32x4){0.f, 0.f, 0.f, 0.f};

    #pragma unroll
    for (int mt = 0; mt < 4; ++mt) {
        const int erow = e0 + 16 * mt + lr;
        short8 ah[3], al[3];
        #pragma unroll
        for (int kc = 0; kc < 3; ++kc)
            ld_frag_split(conn + (size_t)erow * H + 32 * kc + 8 * lg16,
                          ah[kc], al[kc]);
        #pragma unroll
        for (int f = 0; f < 3; ++f) {
            #pragma unroll
            for (int kc = 0; kc < 3; ++kc) {
                acc[mt][f] = __builtin_amdgcn_mfma_f32_16x16x32_bf16(
                                 ah[kc], bwl[f][kc], acc[mt][f], 0, 0, 0);
                acc[mt][f] = __builtin_amdgcn_mfma_f32_16x16x32_bf16(
                                 al[kc], bwh[f][kc], acc[mt][f], 0, 0, 0);
                acc[mt][f] = __builtin_amdgcn_mfma_f32_16x16x32_bf16(
                                 ah[kc], bwh[f][kc], acc[mt][f], 0, 0, 0);
            }
        }
    }

    // ---- write Eh (+bias) to LDS ----
    #pragma unroll
    for (int mt = 0; mt < 4; ++mt) {
        #pragma unroll
        for (int f = 0; f < 3; ++f) {
            const int col = 16 * (3 * wave + f) + lr;
            const float bias = eb[col];
            #pragma unroll
            for (int r = 0; r < 4; ++r) {
                const int row = 16 * mt + 4 * lg16 + r;
                eh[row * EH_LD + col] = acc[mt][f][r] + bias;
            }
        }
    }
    __syncthreads();

    // ---- pointwise: lane q4 owns cols [24*q4, 24*q4+24); float4 I/O ----
    const int e_loc = t >> 2;
    const int q4    = t & 3;
    const int e     = e0 + e_loc;
    const int dst   = eidx[e];
    const int src   = eidx[N_EDGES + e];
    const float4* qQ4 = (const float4*)(qkv + (size_t)dst * QKV_N) + 6 * q4;
    const float4* qK4 = (const float4*)(qkv + (size_t)src * QKV_N + H) + 6 * q4;
    float4*       oe4 = (float4*)(out_e + (size_t)e * H) + 6 * q4;
    const float*  ehr = &eh[e_loc * EH_LD + 24 * q4];

    #pragma unroll
    for (int i = 0; i < 6; ++i) {
        const float4 q  = qQ4[i];
        const float4 k  = qK4[i];
        const float4 w4 = *(const float4*)(ehr + 4 * i);
        const float4 b4 = *(const float4*)(ehr + 4 * i + H);
        float4 co4;
        #pragma unroll
        for (int jj = 0; jj < 4; ++jj) {
            const float c1 = (q[jj] + k[jj]) * w4[jj];
            const float c2 = copysignf(sqrtf(fabsf(c1)), c1);
            co4[jj] = fmaxf(c2 + b4[jj], 0.f);
        }
        oe4[i] = co4;
    }
}

// ---------------------------------------------------------------------------
// eln: out_e = LN(conn + co) in place. Lane q4 owns 24 contiguous cols.
// ---------------------------------------------------------------------------
__global__ __launch_bounds__(256) void eln_kernel(
    const float* __restrict__ conn,
    const float* __restrict__ ln_g, const float* __restrict__ ln_b,
    float* __restrict__ out_e)
{
    const int tt   = blockIdx.x * 256 + threadIdx.x;
    const size_t e = (size_t)(tt >> 2);
    const int q4   = tt & 3;
    const float4* cn4 = (const float4*)(conn + e * H) + 6 * q4;
    float4*       oe4 = (float4*)(out_e + e * H) + 6 * q4;
    const float4* g4  = (const float4*)ln_g + 6 * q4;
    const float4* b4  = (const float4*)ln_b + 6 * q4;

    float4 v[6];
    float s = 0.f, s2 = 0.f;
    #pragma unroll
    for (int i = 0; i < 6; ++i) {
        const float4 c = cn4[i];
        const float4 o = oe4[i];
        float4 val;
        #pragma unroll
        for (int jj = 0; jj < 4; ++jj) {
            val[jj] = c[jj] + o[jj];
            s += val[jj]; s2 += val[jj] * val[jj];
        }
        v[i] = val;
    }
    s  += __shfl_xor(s, 1);  s  += __shfl_xor(s, 2);
    s2 += __shfl_xor(s2, 1); s2 += __shfl_xor(s2, 2);
    const float mean = s * (1.f / H);
    const float var  = s2 * (1.f / H) - mean * mean;
    const float rs   = rsqrtf(var + 1e-5f);
    #pragma unroll
    for (int i = 0; i < 6; ++i) {
        const float4 g = g4[i], b = b4[i];
        float4 o;
        #pragma unroll
        for (int jj = 0; jj < 4; ++jj)
            o[jj] = (v[i][jj] - mean) * rs * g[jj] + b[jj];
        oe4[i] = o;
    }
}

// ---------------------------------------------------------------------------
// Kernel 3: node path via CSR gather. 384 threads = 4 parity groups x 96 cols.
// Gather: 2x-unrolled prefetch -> 4 independent loads in flight per thread.
// ---------------------------------------------------------------------------
__global__ __launch_bounds__(NT3) void node_kernel(
    const float* __restrict__ x, const float* __restrict__ qkv,
    const float* __restrict__ co_f32,                 // = out_e (holds raw co)
    const int* __restrict__ rowptr, const int* __restrict__ bucket,
    const int* __restrict__ bsrc,
    const float* __restrict__ clw, const float* __restrict__ clb,
    const float* __restrict__ nlw, const float* __restrict__ nlb,
    const float* __restrict__ ln_g, const float* __restrict__ ln_b,
    float* __restrict__ out_h)
{
    __shared__ float pa2[NT3], pe2[NT3];
    __shared__ __align__(16) float ga[H];     // eagg row
    __shared__ __align__(16) float sa[H];     // agg row, then agg+e2
    __shared__ float red0[H], red1[H];
    __shared__ float stats[2];
    const int t   = threadIdx.x;
    const int par = t / H;                    // 0..3
    const int col = t - par * H;              // 0..95

    float w[H];
    if (t < 2 * H) {
        const float* wsrc = (t < H) ? (clw + (size_t)t * H) : (nlw + (size_t)(t - H) * H);
        #pragma unroll
        for (int k4 = 0; k4 < H; k4 += 4) {
            float4 v = *(const float4*)(wsrc + k4);
            w[k4] = v.x; w[k4 + 1] = v.y; w[k4 + 2] = v.z; w[k4 + 3] = v.w;
        }
    }
    const float bias = (t < H) ? clb[t] : ((t < 2 * H) ? nlb[t - H] : 0.f);
    const float lg = (t >= H && t < 2 * H) ? ln_g[t - H] : 0.f;
    const float lb = (t >= H && t < 2 * H) ? ln_b[t - H] : 0.f;

    const int n0 = blockIdx.x * NPB3;
    for (int nn = 0; nn < NPB3; ++nn) {
        const int node = n0 + nn;
        if (node >= N_NODES) break;            // block-uniform
        const int r0 = rowptr[node], r1 = rowptr[node + 1];

        // gather: 4-way parity split, 2x unrolled (4 loads in flight)
        float pa = 0.f, pe = 0.f;
        int j = r0 + par;
        for (; j + 4 < r1; j += 8) {
            const int eA = bucket[j],     sA = bsrc[j];
            const int eB = bucket[j + 4], sB = bsrc[j + 4];
            const float a0 = qkv[(size_t)sA * QKV_N + 2 * H + col];
            const float b0 = co_f32[(size_t)eA * H + col];
            const float a1 = qkv[(size_t)sB * QKV_N + 2 * H + col];
            const float b1 = co_f32[(size_t)eB * H + col];
            pa += a0 + a1; pe += b0 + b1;
        }
        if (j < r1) {
            const int eA = bucket[j], sA = bsrc[j];
            pa += qkv[(size_t)sA * QKV_N + 2 * H + col];
            pe += co_f32[(size_t)eA * H + col];
        }

        __syncthreads();                       // (A) prev iter done with LDS
        pa2[t] = pa; pe2[t] = pe;
        __syncthreads();                       // (B)
        if (t < H)
            ga[t] = pe2[t] + pe2[t + H] + pe2[t + 2 * H] + pe2[t + 3 * H];
        else if (t < 2 * H) {
            const int c = t - H;
            sa[c] = pa2[c] + pa2[c + H] + pa2[c + 2 * H] + pa2[c + 3 * H];
        }
        __syncthreads();                       // (C)

        if (t < H) {                           // e2 GEMV, sa = agg + e2
            float acc = bias;
            #pragma unroll
            for (int k4 = 0; k4 < H; k4 += 4) {
                float4 c = *(const float4*)(ga + k4);
                acc += c.x * w[k4] + c.y * w[k4 + 1] + c.z * w[k4 + 2] + c.w * w[k4 + 3];
            }
            sa[t] += acc;
        }
        __syncthreads();                       // (D)

        float val = 0.f;
        if (t >= H && t < 2 * H) {             // h GEMV + residual
            const int tt = t - H;
            float acc = bias;
            #pragma unroll
            for (int k4 = 0; k4 < H; k4 += 4) {
                float4 c = *(const float4*)(sa + k4);
                acc += c.x * w[k4] + c.y * w[k4 + 1] + c.z * w[k4 + 2] + c.w * w[k4 + 3];
            }
            val = acc + x[(size_t)node * H + tt];
            red0[tt] = val;
            red1[tt] = val * val;
        }
        __syncthreads();                       // (E)

        if (t < 64) {                          // single-wave LN reduce
            float s;
            if (t < 32) s = red0[t] + red0[t + 32] + red0[t + 64];
            else        s = red1[t - 32] + red1[t] + red1[t + 32];
            s += __shfl_xor(s, 1); s += __shfl_xor(s, 2); s += __shfl_xor(s, 4);
            s += __shfl_xor(s, 8); s += __shfl_xor(s, 16);
            if (t == 0)  stats[0] = s;
            if (t == 32) stats[1] = s;
        }
        __syncthreads();                       // (F)

        if (t >= H && t < 2 * H) {
            const float mean = stats[0] * (1.f / H);
            const float var  = stats[1] * (1.f / H) - mean * mean;
            const float r    = rsqrtf(var + 1e-5f);
            out_h[(size_t)node * H + (t - H)] = (val - mean) * r * lg + lb;
        }
    }
}

// ---------------------------------------------------------------------------
extern "C" void kernel_launch(void* const* d_in, const int* in_sizes, int n_in,
                              void* d_out, int out_size, void* d_ws, size_t ws_size,
                              hipStream_t stream) {
    const float* x      = (const float*)d_in[0];
    const float* conn   = (const float*)d_in[1];
    const int*   eidx   = (const int*)  d_in[2];
    const float* qkv_w  = (const float*)d_in[3];
    const float* qkv_b  = (const float*)d_in[4];
    const float* e_w    = (const float*)d_in[5];
    const float* e_b    = (const float*)d_in[6];
    const float* clw    = (const float*)d_in[7];
    const float* clb    = (const float*)d_in[8];
    const float* nlw    = (const float*)d_in[9];
    const float* nlb    = (const float*)d_in[10];
    const float* ln_h_g = (const float*)d_in[11];
    const float* ln_h_b = (const float*)d_in[12];
    const float* ln_e_g = (const float*)d_in[13];
    const float* ln_e_b = (const float*)d_in[14];

    float* out_h = (float*)d_out;                        // 50000*96
    float* out_e = out_h + (size_t)N_NODES * H;          // 800000*96

    // ---- workspace layout: qkv | rowptr | hist | bucket | bsrc  (64.4 MB) ----
    char* base = (char*)d_ws;
    float* qkv = (float*)base;
    size_t off = (size_t)N_NODES * QKV_N * sizeof(float);   // 57.6 MB
    int* rowptr = (int*)(base + off); off += (size_t)(N_NODES + 1) * 4;
    int* hist   = (int*)(base + off); off += (size_t)N_NODES * 4;
    int* bucket = (int*)(base + off); off += (size_t)N_EDGES * 4;
    int* bsrc   = (int*)(base + off);

    hipMemsetAsync(hist, 0, (size_t)N_NODES * 4, stream);

    qkv_kernel    <<<(N_NODES + NPB1 - 1) / NPB1, QKV_N, 0, stream>>>(x, qkv_w, qkv_b, qkv);
    hist_kernel   <<<(N_EDGES + 255) / 256, 256, 0, stream>>>(eidx, hist);
    scan_kernel   <<<1, 1024, 0, stream>>>(hist, rowptr);
    scatter_kernel<<<(N_EDGES + 255) / 256, 256, 0, stream>>>(eidx, hist, bucket, bsrc);

    edge_kernel<<<N_EDGES / TILE_E, 256, 0, stream>>>(conn, eidx, qkv, e_w, e_b, out_e);
    node_kernel<<<(N_NODES + NPB3 - 1) / NPB3, NT3, 0, stream>>>(
        x, qkv, out_e, rowptr, bucket, bsrc,
        clw, clb, nlw, nlb, ln_h_g, ln_h_b, out_h);
    eln_kernel<<<(N_EDGES * 4) / 256, 256, 0, stream>>>(conn, ln_e_g, ln_e_b, out_e);
}

// Round 7
// 1490.405 us; speedup vs baseline: 1.2522x; 1.2522x over previous
//
#include <hip/hip_runtime.h>
#include <math.h>

#define N_NODES 50000
#define N_EDGES 800000
#define H 96
#define QKV_N 288

#define NPB1 32   // nodes per block, qkv kernel
#define NPB3 4    // nodes per block, node kernel (R7: 32 -> 4, grid 1563 -> 12500)

typedef __attribute__((ext_vector_type(8))) short short8;   // 8 bf16 = 4 VGPRs
typedef __attribute__((ext_vector_type(4))) float f32x4;    // MFMA accumulator

// float -> bf16 (RNE)
__device__ __forceinline__ short f2bf(float f) {
    union { float f; unsigned u; } v; v.f = f;
    unsigned r = v.u + 0x7FFFu + ((v.u >> 16) & 1u);
    return (short)(r >> 16);
}
__device__ __forceinline__ float bf2f(unsigned short h) {
    union { unsigned u; float f; } v; v.u = ((unsigned)h) << 16;
    return v.f;
}

// load 8 contiguous f32 -> hi/lo bf16x8 split fragments (bf16x3 trick)
__device__ __forceinline__ void ld_frag_split(const float* __restrict__ p,
                                              short8& hi, short8& lo) {
    float4 a = *(const float4*)p;
    float4 b = *(const float4*)(p + 4);
    float f[8] = {a.x, a.y, a.z, a.w, b.x, b.y, b.z, b.w};
    #pragma unroll
    for (int j = 0; j < 8; ++j) {
        short h = f2bf(f[j]);
        hi[j] = h;
        lo[j] = f2bf(f[j] - bf2f((unsigned short)h));
    }
}

// ---------------------------------------------------------------------------
// Kernel 1: qkv[n, t] = dot(x[n, :], qkv_w[t, :]) + qkv_b[t]   (t < 288)
// ---------------------------------------------------------------------------
__global__ __launch_bounds__(QKV_N) void qkv_kernel(
    const float* __restrict__ x, const float* __restrict__ qw,
    const float* __restrict__ qb, float* __restrict__ qkv)
{
    __shared__ __align__(16) float xs[H];
    const int t = threadIdx.x;

    float w[H];
    #pragma unroll
    for (int k4 = 0; k4 < H; k4 += 4) {
        float4 v = *(const float4*)(qw + (size_t)t * H + k4);
        w[k4] = v.x; w[k4 + 1] = v.y; w[k4 + 2] = v.z; w[k4 + 3] = v.w;
    }
    const float bias = qb[t];

    const int n0 = blockIdx.x * NPB1;
    for (int nn = 0; nn < NPB1; ++nn) {
        const int node = n0 + nn;
        if (node >= N_NODES) break;          // block-uniform
        __syncthreads();
        if (t < H) xs[t] = x[(size_t)node * H + t];
        __syncthreads();
        float acc = bias;
        #pragma unroll
        for (int k4 = 0; k4 < H; k4 += 4) {
            float4 c = *(const float4*)(xs + k4);
            acc += c.x * w[k4] + c.y * w[k4 + 1] + c.z * w[k4 + 2] + c.w * w[k4 + 3];
        }
        qkv[(size_t)node * QKV_N + t] = acc;
    }
}

// ---------------------------------------------------------------------------
// CSR build: histogram -> scan -> scatter   (proven R4/R5)
// ---------------------------------------------------------------------------
__global__ __launch_bounds__(256) void hist_kernel(const int* __restrict__ eidx,
                                                   int* __restrict__ hist) {
    const int e = blockIdx.x * 256 + threadIdx.x;
    if (e < N_EDGES) atomicAdd(&hist[eidx[e]], 1);
}

#define SCAN_CH 49   // 1024*49 = 50176 >= 50000
__global__ __launch_bounds__(1024) void scan_kernel(int* __restrict__ hist,
                                                    int* __restrict__ rowptr) {
    __shared__ int sums[1024];
    const int t = threadIdx.x;
    const int st = t * SCAN_CH;
    int loc = 0;
    for (int k = 0; k < SCAN_CH; ++k) {
        const int i = st + k;
        if (i < N_NODES) loc += hist[i];
    }
    sums[t] = loc;
    __syncthreads();
    for (int off = 1; off < 1024; off <<= 1) {
        int add = (t >= off) ? sums[t - off] : 0;
        __syncthreads();
        sums[t] += add;
        __syncthreads();
    }
    int run = sums[t] - loc;     // exclusive prefix of this thread's chunk
    for (int k = 0; k < SCAN_CH; ++k) {
        const int i = st + k;
        if (i < N_NODES) {
            const int v = hist[i];
            rowptr[i] = run;
            hist[i]   = run;     // hist becomes the scatter cursor
            run += v;
        }
    }
    if (t == 1023) rowptr[N_NODES] = run;   // = N_EDGES
}

__global__ __launch_bounds__(256) void scatter_kernel(const int* __restrict__ eidx,
                                                      int* __restrict__ cursor,
                                                      int* __restrict__ bucket,
                                                      int* __restrict__ bsrc) {
    const int e = blockIdx.x * 256 + threadIdx.x;
    if (e < N_EDGES) {
        const int dst = eidx[e];
        const int src = eidx[N_EDGES + e];
        const int pos = atomicAdd(&cursor[dst], 1);
        bucket[pos] = e;
        bsrc[pos]   = src;
    }
}

// ---------------------------------------------------------------------------
// Kernel 2 (MFMA, bf16x3 split) — unchanged from R6 (edge improved there).
// ---------------------------------------------------------------------------
#define TILE_E 64
#define EH_LD 196

__global__ __launch_bounds__(256) void edge_kernel(
    const float* __restrict__ conn, const int* __restrict__ eidx,
    const float* __restrict__ qkv,
    const float* __restrict__ ew, const float* __restrict__ eb,
    float* __restrict__ out_e)
{
    __shared__ float eh[TILE_E * EH_LD];      // 64 x 196 f32 = 50176 B

    const int t    = threadIdx.x;
    const int wave = t >> 6;
    const int lane = t & 63;
    const int lr   = lane & 15;
    const int lg16 = lane >> 4;

    // ---- B fragments (hi+lo): e_w rows are B^T rows ----
    short8 bwh[3][3], bwl[3][3];
    #pragma unroll
    for (int f = 0; f < 3; ++f) {
        const int tcol = 16 * (3 * wave + f) + lr;
        #pragma unroll
        for (int kc = 0; kc < 3; ++kc)
            ld_frag_split(ew + (size_t)tcol * H + 32 * kc + 8 * lg16,
                          bwh[f][kc], bwl[f][kc]);
    }

    const int e0 = blockIdx.x * TILE_E;

    f32x4 acc[4][3];
    #pragma unroll
    for (int mt = 0; mt < 4; ++mt)
        #pragma unroll
        for (int f = 0; f < 3; ++f)
            acc[mt][f] = (f32x4){0.f, 0.f, 0.f, 0.f};

    #pragma unroll
    for (int mt = 0; mt < 4; ++mt) {
        const int erow = e0 + 16 * mt + lr;
        short8 ah[3], al[3];
        #pragma unroll
        for (int kc = 0; kc < 3; ++kc)
            ld_frag_split(conn + (size_t)erow * H + 32 * kc + 8 * lg16,
                          ah[kc], al[kc]);
        #pragma unroll
        for (int f = 0; f < 3; ++f) {
            #pragma unroll
            for (int kc = 0; kc < 3; ++kc) {
                acc[mt][f] = __builtin_amdgcn_mfma_f32_16x16x32_bf16(
                                 ah[kc], bwl[f][kc], acc[mt][f], 0, 0, 0);
                acc[mt][f] = __builtin_amdgcn_mfma_f32_16x16x32_bf16(
                                 al[kc], bwh[f][kc], acc[mt][f], 0, 0, 0);
                acc[mt][f] = __builtin_amdgcn_mfma_f32_16x16x32_bf16(
                                 ah[kc], bwh[f][kc], acc[mt][f], 0, 0, 0);
            }
        }
    }

    // ---- write Eh (+bias) to LDS ----
    #pragma unroll
    for (int mt = 0; mt < 4; ++mt) {
        #pragma unroll
        for (int f = 0; f < 3; ++f) {
            const int col = 16 * (3 * wave + f) + lr;
            const float bias = eb[col];
            #pragma unroll
            for (int r = 0; r < 4; ++r) {
                const int row = 16 * mt + 4 * lg16 + r;
                eh[row * EH_LD + col] = acc[mt][f][r] + bias;
            }
        }
    }
    __syncthreads();

    // ---- pointwise: lane q4 owns cols [24*q4, 24*q4+24); float4 I/O ----
    const int e_loc = t >> 2;
    const int q4    = t & 3;
    const int e     = e0 + e_loc;
    const int dst   = eidx[e];
    const int src   = eidx[N_EDGES + e];
    const float4* qQ4 = (const float4*)(qkv + (size_t)dst * QKV_N) + 6 * q4;
    const float4* qK4 = (const float4*)(qkv + (size_t)src * QKV_N + H) + 6 * q4;
    float4*       oe4 = (float4*)(out_e + (size_t)e * H) + 6 * q4;
    const float*  ehr = &eh[e_loc * EH_LD + 24 * q4];

    #pragma unroll
    for (int i = 0; i < 6; ++i) {
        const float4 q  = qQ4[i];
        const float4 k  = qK4[i];
        const float4 w4 = *(const float4*)(ehr + 4 * i);
        const float4 b4 = *(const float4*)(ehr + 4 * i + H);
        float4 co4;
        #pragma unroll
        for (int jj = 0; jj < 4; ++jj) {
            const float c1 = (q[jj] + k[jj]) * w4[jj];
            const float c2 = copysignf(sqrtf(fabsf(c1)), c1);
            co4[jj] = fmaxf(c2 + b4[jj], 0.f);
        }
        oe4[i] = co4;
    }
}

// ---------------------------------------------------------------------------
// eln: out_e = LN(conn + co) in place — unchanged from R6.
// ---------------------------------------------------------------------------
__global__ __launch_bounds__(256) void eln_kernel(
    const float* __restrict__ conn,
    const float* __restrict__ ln_g, const float* __restrict__ ln_b,
    float* __restrict__ out_e)
{
    const int tt   = blockIdx.x * 256 + threadIdx.x;
    const size_t e = (size_t)(tt >> 2);
    const int q4   = tt & 3;
    const float4* cn4 = (const float4*)(conn + e * H) + 6 * q4;
    float4*       oe4 = (float4*)(out_e + e * H) + 6 * q4;
    const float4* g4  = (const float4*)ln_g + 6 * q4;
    const float4* b4  = (const float4*)ln_b + 6 * q4;

    float4 v[6];
    float s = 0.f, s2 = 0.f;
    #pragma unroll
    for (int i = 0; i < 6; ++i) {
        const float4 c = cn4[i];
        const float4 o = oe4[i];
        float4 val;
        #pragma unroll
        for (int jj = 0; jj < 4; ++jj) {
            val[jj] = c[jj] + o[jj];
            s += val[jj]; s2 += val[jj] * val[jj];
        }
        v[i] = val;
    }
    s  += __shfl_xor(s, 1);  s  += __shfl_xor(s, 2);
    s2 += __shfl_xor(s2, 1); s2 += __shfl_xor(s2, 2);
    const float mean = s * (1.f / H);
    const float var  = s2 * (1.f / H) - mean * mean;
    const float rs   = rsqrtf(var + 1e-5f);
    #pragma unroll
    for (int i = 0; i < 6; ++i) {
        const float4 g = g4[i], b = b4[i];
        float4 o;
        #pragma unroll
        for (int jj = 0; jj < 4; ++jj)
            o[jj] = (v[i][jj] - mean) * rs * g[jj] + b[jj];
        oe4[i] = o;
    }
}

// ---------------------------------------------------------------------------
// Kernel 3: node path via CSR gather — R5-proven 192-thread version VERBATIM;
// only NPB3 changed (32 -> 4) for 8x more independent block streams.
// ---------------------------------------------------------------------------
__global__ __launch_bounds__(192) void node_kernel(
    const float* __restrict__ x, const float* __restrict__ qkv,
    const float* __restrict__ co_f32,                 // = out_e (holds raw co)
    const int* __restrict__ rowptr, const int* __restrict__ bucket,
    const int* __restrict__ bsrc,
    const float* __restrict__ clw, const float* __restrict__ clb,
    const float* __restrict__ nlw, const float* __restrict__ nlb,
    const float* __restrict__ ln_g, const float* __restrict__ ln_b,
    float* __restrict__ out_h)
{
    __shared__ __align__(16) float ga[H];     // eagg row
    __shared__ __align__(16) float sa[H];     // agg row, then agg+e2
    __shared__ float pa2[192], pe2[192];
    __shared__ float red0[H], red1[H];
    const int t = threadIdx.x;
    const int col = (t < H) ? t : (t - H);
    const int par = (t < H) ? 0 : 1;

    float w[H];
    {
        const float* wsrc = (t < H) ? (clw + (size_t)t * H) : (nlw + (size_t)(t - H) * H);
        #pragma unroll
        for (int k4 = 0; k4 < H; k4 += 4) {
            float4 v = *(const float4*)(wsrc + k4);
            w[k4] = v.x; w[k4 + 1] = v.y; w[k4 + 2] = v.z; w[k4 + 3] = v.w;
        }
    }
    const float bias = (t < H) ? clb[t] : nlb[t - H];
    const float lg = (t >= H) ? ln_g[t - H] : 0.f;
    const float lb = (t >= H) ? ln_b[t - H] : 0.f;

    const int n0 = blockIdx.x * NPB3;
    for (int nn = 0; nn < NPB3; ++nn) {
        const int node = n0 + nn;
        if (node >= N_NODES) break;            // block-uniform
        const int r0 = rowptr[node], r1 = rowptr[node + 1];

        float pa = 0.f, pe = 0.f;
        for (int j = r0 + par; j < r1; j += 2) {
            const int ee = bucket[j];
            const int sv = bsrc[j];
            pa += qkv[(size_t)sv * QKV_N + 2 * H + col];
            pe += co_f32[(size_t)ee * H + col];
        }
        __syncthreads();                       // prior iter done with LDS
        pa2[t] = pa; pe2[t] = pe;
        __syncthreads();
        if (t < H) ga[t]      = pe2[t] + pe2[t + H];        // eagg
        else       sa[t - H]  = pa2[t - H] + pa2[t];        // agg
        __syncthreads();

        if (t < H) {                           // e2 GEMV, sa = agg + e2
            float acc = bias;
            #pragma unroll
            for (int k4 = 0; k4 < H; k4 += 4) {
                float4 c = *(const float4*)(ga + k4);
                acc += c.x * w[k4] + c.y * w[k4 + 1] + c.z * w[k4 + 2] + c.w * w[k4 + 3];
            }
            sa[t] += acc;
        }
        __syncthreads();

        float val = 0.f;
        if (t >= H) {                          // h GEMV + residual
            const int tt = t - H;
            float acc = bias;
            #pragma unroll
            for (int k4 = 0; k4 < H; k4 += 4) {
                float4 c = *(const float4*)(sa + k4);
                acc += c.x * w[k4] + c.y * w[k4 + 1] + c.z * w[k4 + 2] + c.w * w[k4 + 3];
            }
            val = acc + x[(size_t)node * H + tt];
            red0[tt] = val;
            red1[tt] = val * val;
        }
        __syncthreads();
        if (t < 32) { red0[t] += red0[t + 64]; red1[t] += red1[t + 64]; }
        __syncthreads();
        for (int s = 32; s > 0; s >>= 1) {
            if (t < s) { red0[t] += red0[t + s]; red1[t] += red1[t + s]; }
            __syncthreads();
        }
        if (t >= H) {
            const float mean = red0[0] * (1.f / H);
            const float var  = red1[0] * (1.f / H) - mean * mean;
            const float r    = rsqrtf(var + 1e-5f);
            out_h[(size_t)node * H + (t - H)] = (val - mean) * r * lg + lb;
        }
    }
}

// ---------------------------------------------------------------------------
extern "C" void kernel_launch(void* const* d_in, const int* in_sizes, int n_in,
                              void* d_out, int out_size, void* d_ws, size_t ws_size,
                              hipStream_t stream) {
    const float* x      = (const float*)d_in[0];
    const float* conn   = (const float*)d_in[1];
    const int*   eidx   = (const int*)  d_in[2];
    const float* qkv_w  = (const float*)d_in[3];
    const float* qkv_b  = (const float*)d_in[4];
    const float* e_w    = (const float*)d_in[5];
    const float* e_b    = (const float*)d_in[6];
    const float* clw    = (const float*)d_in[7];
    const float* clb    = (const float*)d_in[8];
    const float* nlw    = (const float*)d_in[9];
    const float* nlb    = (const float*)d_in[10];
    const float* ln_h_g = (const float*)d_in[11];
    const float* ln_h_b = (const float*)d_in[12];
    const float* ln_e_g = (const float*)d_in[13];
    const float* ln_e_b = (const float*)d_in[14];

    float* out_h = (float*)d_out;                        // 50000*96
    float* out_e = out_h + (size_t)N_NODES * H;          // 800000*96

    // ---- workspace layout: qkv | rowptr | hist | bucket | bsrc  (64.4 MB) ----
    char* base = (char*)d_ws;
    float* qkv = (float*)base;
    size_t off = (size_t)N_NODES * QKV_N * sizeof(float);   // 57.6 MB
    int* rowptr = (int*)(base + off); off += (size_t)(N_NODES + 1) * 4;
    int* hist   = (int*)(base + off); off += (size_t)N_NODES * 4;
    int* bucket = (int*)(base + off); off += (size_t)N_EDGES * 4;
    int* bsrc   = (int*)(base + off);

    hipMemsetAsync(hist, 0, (size_t)N_NODES * 4, stream);

    qkv_kernel    <<<(N_NODES + NPB1 - 1) / NPB1, QKV_N, 0, stream>>>(x, qkv_w, qkv_b, qkv);
    hist_kernel   <<<(N_EDGES + 255) / 256, 256, 0, stream>>>(eidx, hist);
    scan_kernel   <<<1, 1024, 0, stream>>>(hist, rowptr);
    scatter_kernel<<<(N_EDGES + 255) / 256, 256, 0, stream>>>(eidx, hist, bucket, bsrc);

    edge_kernel<<<N_EDGES / TILE_E, 256, 0, stream>>>(conn, eidx, qkv, e_w, e_b, out_e);
    node_kernel<<<(N_NODES + NPB3 - 1) / NPB3, 192, 0, stream>>>(
        x, qkv, out_e, rowptr, bucket, bsrc,
        clw, clb, nlw, nlb, ln_h_g, ln_h_b, out_h);
    eln_kernel<<<(N_EDGES * 4) / 256, 256, 0, stream>>>(conn, ln_e_g, ln_e_b, out_e);
}